// Round 5
// baseline (151.664 us; speedup 1.0000x reference)
//
#include <hip/hip_runtime.h>

#define BH 64
#define S_ 4096
#define D_ 128
#define SCALE 0.25f  // 1/sqrt(n_heads=16)

typedef __attribute__((ext_vector_type(4))) short short4v;
typedef __attribute__((ext_vector_type(8))) short short8v;
typedef __attribute__((ext_vector_type(4))) float f32x4;

__device__ inline unsigned short f2bf(float x) {
  union { float f; unsigned u; } v; v.f = x;
  unsigned r = v.u + 0x7fff + ((v.u >> 16) & 1);
  return (unsigned short)(r >> 16);
}
__device__ inline short8v cat8(short4v a, short4v b) {
  short8v r;
  r[0] = a[0]; r[1] = a[1]; r[2] = a[2]; r[3] = a[3];
  r[4] = b[0]; r[5] = b[1]; r[6] = b[2]; r[7] = b[3];
  return r;
}
// Hardware transpose read (semantics verified by round-2/3/4 passes).
__device__ inline short4v tr16(unsigned addr) {
  short4v r;
  asm volatile("ds_read_b64_tr_b16 %0, %1" : "=v"(r) : "v"(addr));
  return r;
}
// Truncation-based hi/lo bf16 split of two floats, packed (elem0 in low 16).
__device__ inline void cvt_pair(float x0, float x1, unsigned& hi, unsigned& lo) {
  unsigned u0 = __float_as_uint(x0), u1 = __float_as_uint(x1);
  unsigned m0 = u0 & 0xffff0000u, m1 = u1 & 0xffff0000u;
  hi = m1 | (u0 >> 16);
  float l0 = x0 - __uint_as_float(m0);
  float l1 = x1 - __uint_as_float(m1);
  lo = (__float_as_uint(l1) & 0xffff0000u) | (__float_as_uint(l0) >> 16);
}

// ---------------------------------------------------------------------------
// Phase A: split-K QK^T, split-bf16 (hi/lo) 3-pass MFMA, LDS double-buffered.
// part[ks][bh][d][e] = SCALE * sum_{s in chunk} q[s][d]*k[s][e]
// Per buffer: 4 tiles x [32 s][136 d] bf16 (Qhi Qlo Khi Klo), 272 B rows.
// 512 threads = 8 waves, 4(m) x 2(n); wave owns 32 d x 64 e.
// ONE s_barrier and ONE lgkmcnt(0) per step; global prefetch never drained
// at barriers (raw s_barrier, no vmcnt).
// ---------------------------------------------------------------------------
#define TILE_SH 4352          // shorts per tile
#define TILE_U  2176          // uints per tile
#define TILE_B  (TILE_SH * 2) // bytes per tile
#define BUF_SH  (4 * TILE_SH) // shorts per buffer (4 tiles)
#define BUF_B   (4 * TILE_B)  // bytes per buffer
#define ROW_B 272             // bytes per LDS row
#define ROW_U 68              // uints per LDS row

template <int NKS, bool ATOMIC>
__global__ __launch_bounds__(512, 2) void qk_mfma(const float* __restrict__ q,
                                                  const float* __restrict__ k,
                                                  float* __restrict__ part) {
  constexpr int schunk = S_ / NKS;
  constexpr int nsteps = schunk / 32;
  static_assert(nsteps % 2 == 0, "nsteps must be even (buffer pairing)");
  const int bh = blockIdx.x;
  const int ks = blockIdx.y;
  const float* qb = q + (size_t)bh * S_ * D_ + (size_t)ks * schunk * D_;
  const float* kb = k + (size_t)bh * S_ * D_ + (size_t)ks * schunk * D_;

  __shared__ alignas(16) short lds[2 * BUF_SH];
  unsigned* ldsU0 = (unsigned*)&lds[0];
  unsigned* ldsU1 = (unsigned*)&lds[BUF_SH];
  const unsigned base_u = (unsigned)(uintptr_t)&lds[0];

  const int tid = threadIdx.x;
  const int wv = tid >> 6, lane = tid & 63;
  const int wm = wv & 3;   // m-block: 32 d
  const int wn = wv >> 2;  // n-block: 64 e

  f32x4 acc[2][4];
#pragma unroll
  for (int a = 0; a < 2; ++a)
#pragma unroll
    for (int b = 0; b < 4; ++b) acc[a][b] = (f32x4){0.f, 0.f, 0.f, 0.f};

  const int lrow = ((lane >> 4) << 2) + ((lane & 15) >> 2);
  const unsigned trbase = base_u + (unsigned)lrow * ROW_B + (unsigned)(lane & 3) * 8;
  const unsigned aQ0 = trbase;                 // buf0 tiles 0 (hi), 1 (lo)
  const unsigned aK0 = trbase + 2u * TILE_B;   // buf0 tiles 2 (hi), 3 (lo)
  const unsigned aQ1 = aQ0 + BUF_B;            // buf1
  const unsigned aK1 = aK0 + BUF_B;

  // per-thread staging geometry
  const int r0 = tid >> 5;           // rows 0..15
  const int r1 = (tid + 512) >> 5;   // rows 16..31
  const int c4 = tid & 31;

  float4 qr[2], kr[2];
  auto load_step = [&](int st) {
    size_t o0 = (size_t)(st * 32 + r0) * D_ + c4 * 4;
    size_t o1 = (size_t)(st * 32 + r1) * D_ + c4 * 4;
    qr[0] = *(const float4*)(qb + o0);
    qr[1] = *(const float4*)(qb + o1);
    kr[0] = *(const float4*)(kb + o0);
    kr[1] = *(const float4*)(kb + o1);
  };
  auto cvt_store = [&](unsigned* bufU) {
#pragma unroll
    for (int i = 0; i < 2; ++i) {
      int row = i ? r1 : r0;
      unsigned* p = bufU + row * ROW_U + c4 * 2;
      float4 xq = qr[i], xk = kr[i];
      unsigned h0, l0, h1, l1;
      cvt_pair(xq.x, xq.y, h0, l0);
      cvt_pair(xq.z, xq.w, h1, l1);
      *(uint2*)(p) = make_uint2(h0, h1);
      *(uint2*)(p + TILE_U) = make_uint2(l0, l1);
      cvt_pair(xk.x, xk.y, h0, l0);
      cvt_pair(xk.z, xk.w, h1, l1);
      *(uint2*)(p + 2 * TILE_U) = make_uint2(h0, h1);
      *(uint2*)(p + 3 * TILE_U) = make_uint2(l0, l1);
    }
  };

  // one pipeline step: tr-read cur buffer, stage st+1 into other buffer,
  // issue loads for st+2, single drain, MFMA, single barrier.
  auto iter = [&](int st, unsigned aQb, unsigned aKb, unsigned* stageU) {
    short4v Bf[4][2][2];
#pragma unroll
    for (int b = 0; b < 4; ++b) {
      unsigned cb = (unsigned)(wn * 4 + b) * 32;
#pragma unroll
      for (int ver = 0; ver < 2; ++ver)
#pragma unroll
        for (int kh = 0; kh < 2; ++kh)
          Bf[b][ver][kh] = tr16(aKb + ver * TILE_B + kh * (16 * ROW_B) + cb);
    }
    short4v Af[2][2][2];
#pragma unroll
    for (int a = 0; a < 2; ++a) {
      unsigned cb = (unsigned)(wm * 2 + a) * 32;
#pragma unroll
      for (int ver = 0; ver < 2; ++ver)
#pragma unroll
        for (int kh = 0; kh < 2; ++kh)
          Af[a][ver][kh] = tr16(aQb + ver * TILE_B + kh * (16 * ROW_B) + cb);
    }
    if (st + 1 < nsteps) cvt_store(stageU);   // consumes qr/kr (chunk st+1)
    if (st + 2 < nsteps) load_step(st + 2);   // issue; stays in flight
    asm volatile("s_waitcnt lgkmcnt(0)" ::: "memory");
    __builtin_amdgcn_sched_barrier(0);
#pragma unroll
    for (int a = 0; a < 2; ++a) {
      short8v ah = cat8(Af[a][0][0], Af[a][0][1]);
      short8v al = cat8(Af[a][1][0], Af[a][1][1]);
#pragma unroll
      for (int b = 0; b < 4; ++b) {
        short8v bh_ = cat8(Bf[b][0][0], Bf[b][0][1]);
        short8v bl_ = cat8(Bf[b][1][0], Bf[b][1][1]);
        acc[a][b] = __builtin_amdgcn_mfma_f32_16x16x32_bf16(ah, bh_, acc[a][b], 0, 0, 0);
        acc[a][b] = __builtin_amdgcn_mfma_f32_16x16x32_bf16(ah, bl_, acc[a][b], 0, 0, 0);
        acc[a][b] = __builtin_amdgcn_mfma_f32_16x16x32_bf16(al, bh_, acc[a][b], 0, 0, 0);
      }
    }
    __builtin_amdgcn_s_barrier();
  };

  // prologue: stage chunk 0 into buf0, issue loads for chunk 1
  load_step(0);
  cvt_store(ldsU0);
  if (nsteps > 1) load_step(1);
  asm volatile("s_waitcnt lgkmcnt(0)" ::: "memory");
  __builtin_amdgcn_s_barrier();

  for (int st = 0; st < nsteps; st += 2) {
    iter(st, aQ0, aK0, ldsU1);
    iter(st + 1, aQ1, aK1, ldsU0);
  }

  // epilogue: D layout col=lane&15, row=(lane>>4)*4+reg
  if (!ATOMIC) {
    float* dst = part + ((size_t)ks * BH + bh) * D_ * D_;
#pragma unroll
    for (int a = 0; a < 2; ++a)
#pragma unroll
      for (int b = 0; b < 4; ++b) {
        int e = (wn * 4 + b) * 16 + (lane & 15);
#pragma unroll
        for (int r = 0; r < 4; ++r) {
          int d = (wm * 2 + a) * 16 + ((lane >> 4) << 2) + r;
          dst[(size_t)d * D_ + e] = acc[a][b][r] * SCALE;
        }
      }
  } else {
    float* dst = part + (size_t)bh * D_ * D_;
#pragma unroll
    for (int a = 0; a < 2; ++a)
#pragma unroll
      for (int b = 0; b < 4; ++b) {
        int e = (wn * 4 + b) * 16 + (lane & 15);
#pragma unroll
        for (int r = 0; r < 4; ++r) {
          int d = (wm * 2 + a) * 16 + ((lane >> 4) << 2) + r;
          atomicAdd(&dst[(size_t)d * D_ + e], acc[a][b][r] * SCALE);
        }
      }
  }
}

// ---------------------------------------------------------------------------
// Phase B: combine partials + row softmax -> P as bf16 (linear [d][e])
// ---------------------------------------------------------------------------
template <int NKS>
__global__ __launch_bounds__(256) void softmax_k(const float* __restrict__ part,
                                                 short* __restrict__ Pg) {
  const int bh = blockIdx.x;
  const int wv = threadIdx.x >> 6, lane = threadIdx.x & 63;
  const size_t kstride = (size_t)BH * D_ * D_;
  const float* base = part + (size_t)bh * D_ * D_;
  short* dst = Pg + (size_t)bh * D_ * D_;
#pragma unroll
  for (int i = 0; i < 8; ++i) {
    int d = blockIdx.y * 32 + wv * 8 + i;
    float v0 = 0.f, v1 = 0.f;
    for (int ks2 = 0; ks2 < NKS; ++ks2) {
      const float* row = base + ks2 * kstride + (size_t)d * D_;
      v0 += row[lane];
      v1 += row[lane + 64];
    }
    float m = fmaxf(v0, v1);
#pragma unroll
    for (int off = 32; off; off >>= 1) m = fmaxf(m, __shfl_xor(m, off, 64));
    float e0 = __expf(v0 - m), e1 = __expf(v1 - m);
    float s = e0 + e1;
#pragma unroll
    for (int off = 32; off; off >>= 1) s += __shfl_xor(s, off, 64);
    float inv = 1.f / s;
    dst[(size_t)d * D_ + lane] = (short)f2bf(e0 * inv);
    dst[(size_t)d * D_ + lane + 64] = (short)f2bf(e1 * inv);
  }
}

// ---------------------------------------------------------------------------
// Phase C: out[d][s] = sum_e P[d][e] * v[s][e] — bf16 MFMA over contiguous e.
// ---------------------------------------------------------------------------
__global__ __launch_bounds__(256) void pv_mfma(const short* __restrict__ Pg,
                                               const float* __restrict__ v,
                                               float* __restrict__ out) {
  const int bh = blockIdx.x;
  const int s0 = blockIdx.y * 128;
  const float* vb = v + (size_t)bh * S_ * D_;
  __shared__ alignas(16) short P_lds[128 * 136];
  __shared__ alignas(16) short V_lds[128 * 36];
  const int tid = threadIdx.x;
  const int wv = tid >> 6, lane = tid & 63;

  const short* Pb = Pg + (size_t)bh * D_ * D_;
#pragma unroll
  for (int i = 0; i < 8; ++i) {
    int idx8 = tid + i * 256;
    int row = idx8 >> 4, c8 = idx8 & 15;
    short8v val = *(const short8v*)(Pb + row * 128 + c8 * 8);
    *(short8v*)(P_lds + row * 136 + c8 * 8) = val;
  }

  f32x4 acc[8][2];
#pragma unroll
  for (int i = 0; i < 8; ++i)
#pragma unroll
    for (int j = 0; j < 2; ++j) acc[i][j] = (f32x4){0.f, 0.f, 0.f, 0.f};

#pragma unroll
  for (int es = 0; es < 4; ++es) {
    __syncthreads();
#pragma unroll
    for (int i = 0; i < 4; ++i) {
      int idx4 = tid + i * 256;
      int s = idx4 >> 3, c4 = idx4 & 7;
      float4 x = *(const float4*)(vb + (size_t)(s0 + s) * D_ + es * 32 + c4 * 4);
      short4v h;
      h[0] = (short)f2bf(x.x); h[1] = (short)f2bf(x.y);
      h[2] = (short)f2bf(x.z); h[3] = (short)f2bf(x.w);
      *(short4v*)(V_lds + s * 36 + c4 * 4) = h;
    }
    __syncthreads();

    short8v a[8];
#pragma unroll
    for (int mt = 0; mt < 8; ++mt) {
      int d = mt * 16 + (lane & 15);
      const short* pr = P_lds + d * 136 + es * 32 + ((lane >> 4) << 2);
      a[mt] = cat8(*(const short4v*)pr, *(const short4v*)(pr + 16));
    }
#pragma unroll
    for (int nl = 0; nl < 2; ++nl) {
      int srow = (wv * 2 + nl) * 16 + (lane & 15);
      const short* vr = V_lds + srow * 36 + ((lane >> 4) << 2);
      short8v b = cat8(*(const short4v*)vr, *(const short4v*)(vr + 16));
#pragma unroll
      for (int mt = 0; mt < 8; ++mt)
        acc[mt][nl] = __builtin_amdgcn_mfma_f32_16x16x32_bf16(a[mt], b, acc[mt][nl], 0, 0, 0);
    }
  }

  float* ob = out + (size_t)bh * D_ * S_ + s0;
#pragma unroll
  for (int mt = 0; mt < 8; ++mt)
#pragma unroll
    for (int nl = 0; nl < 2; ++nl) {
      int sc = (wv * 2 + nl) * 16 + (lane & 15);
#pragma unroll
      for (int r = 0; r < 4; ++r) {
        int d = mt * 16 + ((lane >> 4) << 2) + r;
        ob[(size_t)d * S_ + sc] = acc[mt][nl][r];
      }
    }
}

extern "C" void kernel_launch(void* const* d_in, const int* in_sizes, int n_in,
                              void* d_out, int out_size, void* d_ws,
                              size_t ws_size, hipStream_t stream) {
  const float* q = (const float*)d_in[0];
  const float* k = (const float*)d_in[1];
  const float* v = (const float*)d_in[2];
  float* out = (float*)d_out;
  char* ws = (char*)d_ws;

  const size_t PART1 = (size_t)BH * D_ * D_ * sizeof(float);  // 4 MiB
  const size_t PSZ = (size_t)BH * D_ * D_ * sizeof(short);    // 2 MiB

  if (ws_size >= 8 * PART1 + PSZ) {
    float* part = (float*)ws;
    short* Pg = (short*)(ws + 8 * PART1);
    qk_mfma<8, false><<<dim3(BH, 8), 512, 0, stream>>>(q, k, part);
    softmax_k<8><<<dim3(BH, 4), 256, 0, stream>>>(part, Pg);
    pv_mfma<<<dim3(BH, 32), 256, 0, stream>>>(Pg, v, out);
  } else {
    float* part = (float*)ws;
    short* Pg = (short*)(ws + PART1);
    hipMemsetAsync(ws, 0, PART1, stream);
    qk_mfma<16, true><<<dim3(BH, 16), 512, 0, stream>>>(q, k, part);
    softmax_k<1><<<dim3(BH, 4), 256, 0, stream>>>(part, Pg);
    pv_mfma<<<dim3(BH, 32), 256, 0, stream>>>(Pg, v, out);
  }
}

// Round 6
// 149.026 us; speedup vs baseline: 1.0177x; 1.0177x over previous
//
#include <hip/hip_runtime.h>

#define BH 64
#define S_ 4096
#define D_ 128
#define SCALE 0.25f  // 1/sqrt(n_heads=16)

typedef __attribute__((ext_vector_type(4))) short short4v;
typedef __attribute__((ext_vector_type(8))) short short8v;
typedef __attribute__((ext_vector_type(4))) float f32x4;

__device__ inline unsigned short f2bf(float x) {
  union { float f; unsigned u; } v; v.f = x;
  unsigned r = v.u + 0x7fff + ((v.u >> 16) & 1);
  return (unsigned short)(r >> 16);
}
__device__ inline short8v cat8(short4v a, short4v b) {
  short8v r;
  r[0] = a[0]; r[1] = a[1]; r[2] = a[2]; r[3] = a[3];
  r[4] = b[0]; r[5] = b[1]; r[6] = b[2]; r[7] = b[3];
  return r;
}
// Hardware transpose read (semantics verified by round-2..5 passes).
__device__ inline short4v tr16(unsigned addr) {
  short4v r;
  asm volatile("ds_read_b64_tr_b16 %0, %1" : "=v"(r) : "v"(addr));
  return r;
}
// Truncation-based hi/lo bf16 split of two floats, packed (elem0 in low 16).
__device__ inline void cvt_pair(float x0, float x1, unsigned& hi, unsigned& lo) {
  unsigned u0 = __float_as_uint(x0), u1 = __float_as_uint(x1);
  unsigned m0 = u0 & 0xffff0000u, m1 = u1 & 0xffff0000u;
  hi = m1 | (u0 >> 16);
  float l0 = x0 - __uint_as_float(m0);
  float l1 = x1 - __uint_as_float(m1);
  lo = (__float_as_uint(l1) & 0xffff0000u) | (__float_as_uint(l0) >> 16);
}

// ---------------------------------------------------------------------------
// Phase A: split-K QK^T, split-bf16 (hi/lo) 3-pass MFMA, LDS double-buffered.
// part[ks][bh][d][e] = SCALE * sum_{s in chunk} q[s][d]*k[s][e]
//
// LDS layout (NEW): each 32(k) x 128(col) bf16 tile stored as 4x16 subtiles:
//   subtile (kg, cb) = M[kg*4 .. kg*4+3][cb*16 .. cb*16+15], contiguous 128 B
//   at tile_base + (kg*8 + cb)*128.  One subtile = all 32 banks exactly once
//   per quarter-wave -> tr-reads conflict-free.  Staging is LINEAR: thread t
//   writes LDS bytes [8t, 8t+8) of each tile (consecutive banks, conflict-
//   free), with the global load permuted so thread t holds the matching
//   element block:  slot s -> row = (s>>7)*4 + ((s>>2)&3),
//                            col = ((s>>4)&7)*16 + (s&3)*4      (bijection).
// tr-read per-lane addr: (l>>4)*1024 + ((l&15)>>2)*32 + (l&3)*8
//   + compile-time (ver*TILE + kh*4096 + cb*128); delivers lane l elem j =
//   M[k = kh*16 + (l>>4)*4 + j][cb*16 + (l&15)] — identical fragments to the
//   verified round-2..5 mapping.
// ---------------------------------------------------------------------------
#define TILE_B2 8192            // bytes per tile
#define TILE_U2 2048            // uints per tile
#define TILE_SH2 4096           // shorts per tile
#define BUF_B2  (4 * TILE_B2)   // 32768 B per buffer (Qhi Qlo Khi Klo)
#define BUF_SH2 (4 * TILE_SH2)  // shorts per buffer

template <int NKS, bool ATOMIC>
__global__ __launch_bounds__(512, 2) void qk_mfma(const float* __restrict__ q,
                                                  const float* __restrict__ k,
                                                  float* __restrict__ part) {
  constexpr int schunk = S_ / NKS;
  constexpr int nsteps = schunk / 32;
  static_assert(nsteps % 2 == 0, "nsteps must be even (buffer pairing)");
  const int bh = blockIdx.x;
  const int ks = blockIdx.y;
  const float* qb = q + (size_t)bh * S_ * D_ + (size_t)ks * schunk * D_;
  const float* kb = k + (size_t)bh * S_ * D_ + (size_t)ks * schunk * D_;

  __shared__ alignas(16) short lds[2 * BUF_SH2];
  unsigned* ldsU0 = (unsigned*)&lds[0];
  unsigned* ldsU1 = (unsigned*)&lds[BUF_SH2];
  const unsigned base_u = (unsigned)(uintptr_t)&lds[0];

  const int tid = threadIdx.x;
  const int wv = tid >> 6, lane = tid & 63;
  const int wm = wv & 3;   // m-block: 32 d
  const int wn = wv >> 2;  // n-block: 64 e

  f32x4 acc[2][4];
#pragma unroll
  for (int a = 0; a < 2; ++a)
#pragma unroll
    for (int b = 0; b < 4; ++b) acc[a][b] = (f32x4){0.f, 0.f, 0.f, 0.f};

  // tr-read per-lane constant
  const unsigned lconst = ((unsigned)(lane >> 4) << 10) |
                          ((unsigned)((lane & 15) >> 2) << 5) |
                          ((unsigned)(lane & 3) << 3);
  const unsigned trbase = base_u + lconst;
  const unsigned aQ0 = trbase;                  // buf0: Qhi at 0, Qlo at +TILE_B2
  const unsigned aK0 = trbase + 2u * TILE_B2;   // buf0: Khi, Klo
  const unsigned aQ1 = aQ0 + BUF_B2;            // buf1
  const unsigned aK1 = aK0 + BUF_B2;

  // staging geometry: thread t owns linear slots t and t+512 of each tile
  const int row0 = ((tid >> 7) << 2) | ((tid >> 2) & 3);
  const int col0 = (((tid >> 4) & 7) << 4) | ((tid & 3) << 2);

  float4 qr[2], kr[2];
  auto load_step = [&](int st) {
    size_t o0 = (size_t)(st * 32 + row0) * D_ + col0;
    size_t o1 = o0 + (size_t)16 * D_;   // slot t+512 -> row+16, same col
    qr[0] = *(const float4*)(qb + o0);
    qr[1] = *(const float4*)(qb + o1);
    kr[0] = *(const float4*)(kb + o0);
    kr[1] = *(const float4*)(kb + o1);
  };
  auto cvt_store = [&](unsigned* bufU) {
#pragma unroll
    for (int i = 0; i < 2; ++i) {
      unsigned off = (unsigned)(tid + i * 512) * 2;  // uint index of 8B slot
      unsigned h0, l0, h1, l1;
      cvt_pair(qr[i].x, qr[i].y, h0, l0);
      cvt_pair(qr[i].z, qr[i].w, h1, l1);
      *(uint2*)(bufU + off) = make_uint2(h0, h1);
      *(uint2*)(bufU + TILE_U2 + off) = make_uint2(l0, l1);
      cvt_pair(kr[i].x, kr[i].y, h0, l0);
      cvt_pair(kr[i].z, kr[i].w, h1, l1);
      *(uint2*)(bufU + 2 * TILE_U2 + off) = make_uint2(h0, h1);
      *(uint2*)(bufU + 3 * TILE_U2 + off) = make_uint2(l0, l1);
    }
  };

  // one pipeline step: tr-read cur buffer, stage st+1 into other buffer,
  // issue loads for st+2, single drain, MFMA, single barrier.
  auto iter = [&](int st, unsigned aQb, unsigned aKb, unsigned* stageU) {
    short4v Bf[4][2][2];
#pragma unroll
    for (int b = 0; b < 4; ++b) {
      unsigned cb = (unsigned)(wn * 4 + b) << 7;
#pragma unroll
      for (int ver = 0; ver < 2; ++ver)
#pragma unroll
        for (int kh = 0; kh < 2; ++kh)
          Bf[b][ver][kh] = tr16(aKb + ver * TILE_B2 + kh * 4096 + cb);
    }
    short4v Af[2][2][2];
#pragma unroll
    for (int a = 0; a < 2; ++a) {
      unsigned cb = (unsigned)(wm * 2 + a) << 7;
#pragma unroll
      for (int ver = 0; ver < 2; ++ver)
#pragma unroll
        for (int kh = 0; kh < 2; ++kh)
          Af[a][ver][kh] = tr16(aQb + ver * TILE_B2 + kh * 4096 + cb);
    }
    if (st + 1 < nsteps) cvt_store(stageU);   // consumes qr/kr (chunk st+1)
    if (st + 2 < nsteps) load_step(st + 2);   // issue; stays in flight
    asm volatile("s_waitcnt lgkmcnt(0)" ::: "memory");
    __builtin_amdgcn_sched_barrier(0);
#pragma unroll
    for (int a = 0; a < 2; ++a) {
      short8v ah = cat8(Af[a][0][0], Af[a][0][1]);
      short8v al = cat8(Af[a][1][0], Af[a][1][1]);
#pragma unroll
      for (int b = 0; b < 4; ++b) {
        short8v bh_ = cat8(Bf[b][0][0], Bf[b][0][1]);
        short8v bl_ = cat8(Bf[b][1][0], Bf[b][1][1]);
        acc[a][b] = __builtin_amdgcn_mfma_f32_16x16x32_bf16(ah, bh_, acc[a][b], 0, 0, 0);
        acc[a][b] = __builtin_amdgcn_mfma_f32_16x16x32_bf16(ah, bl_, acc[a][b], 0, 0, 0);
        acc[a][b] = __builtin_amdgcn_mfma_f32_16x16x32_bf16(al, bh_, acc[a][b], 0, 0, 0);
      }
    }
    __builtin_amdgcn_s_barrier();
  };

  // prologue: stage chunk 0 into buf0, issue loads for chunk 1
  load_step(0);
  cvt_store(ldsU0);
  if (nsteps > 1) load_step(1);
  asm volatile("s_waitcnt lgkmcnt(0)" ::: "memory");
  __builtin_amdgcn_s_barrier();

  for (int st = 0; st < nsteps; st += 2) {
    iter(st, aQ0, aK0, ldsU1);
    iter(st + 1, aQ1, aK1, ldsU0);
  }

  // epilogue: D layout col=lane&15, row=(lane>>4)*4+reg
  if (!ATOMIC) {
    float* dst = part + ((size_t)ks * BH + bh) * D_ * D_;
#pragma unroll
    for (int a = 0; a < 2; ++a)
#pragma unroll
      for (int b = 0; b < 4; ++b) {
        int e = (wn * 4 + b) * 16 + (lane & 15);
#pragma unroll
        for (int r = 0; r < 4; ++r) {
          int d = (wm * 2 + a) * 16 + ((lane >> 4) << 2) + r;
          dst[(size_t)d * D_ + e] = acc[a][b][r] * SCALE;
        }
      }
  } else {
    float* dst = part + (size_t)bh * D_ * D_;
#pragma unroll
    for (int a = 0; a < 2; ++a)
#pragma unroll
      for (int b = 0; b < 4; ++b) {
        int e = (wn * 4 + b) * 16 + (lane & 15);
#pragma unroll
        for (int r = 0; r < 4; ++r) {
          int d = (wm * 2 + a) * 16 + ((lane >> 4) << 2) + r;
          atomicAdd(&dst[(size_t)d * D_ + e], acc[a][b][r] * SCALE);
        }
      }
  }
}

// ---------------------------------------------------------------------------
// Phase B: combine partials + row softmax -> P as bf16 (linear [d][e])
// ---------------------------------------------------------------------------
template <int NKS>
__global__ __launch_bounds__(256) void softmax_k(const float* __restrict__ part,
                                                 short* __restrict__ Pg) {
  const int bh = blockIdx.x;
  const int wv = threadIdx.x >> 6, lane = threadIdx.x & 63;
  const size_t kstride = (size_t)BH * D_ * D_;
  const float* base = part + (size_t)bh * D_ * D_;
  short* dst = Pg + (size_t)bh * D_ * D_;
#pragma unroll
  for (int i = 0; i < 8; ++i) {
    int d = blockIdx.y * 32 + wv * 8 + i;
    float v0 = 0.f, v1 = 0.f;
    for (int ks2 = 0; ks2 < NKS; ++ks2) {
      const float* row = base + ks2 * kstride + (size_t)d * D_;
      v0 += row[lane];
      v1 += row[lane + 64];
    }
    float m = fmaxf(v0, v1);
#pragma unroll
    for (int off = 32; off; off >>= 1) m = fmaxf(m, __shfl_xor(m, off, 64));
    float e0 = __expf(v0 - m), e1 = __expf(v1 - m);
    float s = e0 + e1;
#pragma unroll
    for (int off = 32; off; off >>= 1) s += __shfl_xor(s, off, 64);
    float inv = 1.f / s;
    dst[(size_t)d * D_ + lane] = (short)f2bf(e0 * inv);
    dst[(size_t)d * D_ + lane + 64] = (short)f2bf(e1 * inv);
  }
}

// ---------------------------------------------------------------------------
// Phase C: out[d][s] = sum_e P[d][e] * v[s][e] — bf16 MFMA over contiguous e.
// ---------------------------------------------------------------------------
__global__ __launch_bounds__(256) void pv_mfma(const short* __restrict__ Pg,
                                               const float* __restrict__ v,
                                               float* __restrict__ out) {
  const int bh = blockIdx.x;
  const int s0 = blockIdx.y * 128;
  const float* vb = v + (size_t)bh * S_ * D_;
  __shared__ alignas(16) short P_lds[128 * 136];
  __shared__ alignas(16) short V_lds[128 * 36];
  const int tid = threadIdx.x;
  const int wv = tid >> 6, lane = tid & 63;

  const short* Pb = Pg + (size_t)bh * D_ * D_;
#pragma unroll
  for (int i = 0; i < 8; ++i) {
    int idx8 = tid + i * 256;
    int row = idx8 >> 4, c8 = idx8 & 15;
    short8v val = *(const short8v*)(Pb + row * 128 + c8 * 8);
    *(short8v*)(P_lds + row * 136 + c8 * 8) = val;
  }

  f32x4 acc[8][2];
#pragma unroll
  for (int i = 0; i < 8; ++i)
#pragma unroll
    for (int j = 0; j < 2; ++j) acc[i][j] = (f32x4){0.f, 0.f, 0.f, 0.f};

#pragma unroll
  for (int es = 0; es < 4; ++es) {
    __syncthreads();
#pragma unroll
    for (int i = 0; i < 4; ++i) {
      int idx4 = tid + i * 256;
      int s = idx4 >> 3, c4 = idx4 & 7;
      float4 x = *(const float4*)(vb + (size_t)(s0 + s) * D_ + es * 32 + c4 * 4);
      short4v h;
      h[0] = (short)f2bf(x.x); h[1] = (short)f2bf(x.y);
      h[2] = (short)f2bf(x.z); h[3] = (short)f2bf(x.w);
      *(short4v*)(V_lds + s * 36 + c4 * 4) = h;
    }
    __syncthreads();

    short8v a[8];
#pragma unroll
    for (int mt = 0; mt < 8; ++mt) {
      int d = mt * 16 + (lane & 15);
      const short* pr = P_lds + d * 136 + es * 32 + ((lane >> 4) << 2);
      a[mt] = cat8(*(const short4v*)pr, *(const short4v*)(pr + 16));
    }
#pragma unroll
    for (int nl = 0; nl < 2; ++nl) {
      int srow = (wv * 2 + nl) * 16 + (lane & 15);
      const short* vr = V_lds + srow * 36 + ((lane >> 4) << 2);
      short8v b = cat8(*(const short4v*)vr, *(const short4v*)(vr + 16));
#pragma unroll
      for (int mt = 0; mt < 8; ++mt)
        acc[mt][nl] = __builtin_amdgcn_mfma_f32_16x16x32_bf16(a[mt], b, acc[mt][nl], 0, 0, 0);
    }
  }

  float* ob = out + (size_t)bh * D_ * S_ + s0;
#pragma unroll
  for (int mt = 0; mt < 8; ++mt)
#pragma unroll
    for (int nl = 0; nl < 2; ++nl) {
      int sc = (wv * 2 + nl) * 16 + (lane & 15);
#pragma unroll
      for (int r = 0; r < 4; ++r) {
        int d = mt * 16 + ((lane >> 4) << 2) + r;
        ob[(size_t)d * S_ + sc] = acc[mt][nl][r];
      }
    }
}

extern "C" void kernel_launch(void* const* d_in, const int* in_sizes, int n_in,
                              void* d_out, int out_size, void* d_ws,
                              size_t ws_size, hipStream_t stream) {
  const float* q = (const float*)d_in[0];
  const float* k = (const float*)d_in[1];
  const float* v = (const float*)d_in[2];
  float* out = (float*)d_out;
  char* ws = (char*)d_ws;

  const size_t PART1 = (size_t)BH * D_ * D_ * sizeof(float);  // 4 MiB
  const size_t PSZ = (size_t)BH * D_ * D_ * sizeof(short);    // 2 MiB

  if (ws_size >= 8 * PART1 + PSZ) {
    float* part = (float*)ws;
    short* Pg = (short*)(ws + 8 * PART1);
    qk_mfma<8, false><<<dim3(BH, 8), 512, 0, stream>>>(q, k, part);
    softmax_k<8><<<dim3(BH, 4), 256, 0, stream>>>(part, Pg);
    pv_mfma<<<dim3(BH, 32), 256, 0, stream>>>(Pg, v, out);
  } else {
    float* part = (float*)ws;
    short* Pg = (short*)(ws + PART1);
    hipMemsetAsync(ws, 0, PART1, stream);
    qk_mfma<16, true><<<dim3(BH, 16), 512, 0, stream>>>(q, k, part);
    softmax_k<1><<<dim3(BH, 4), 256, 0, stream>>>(part, Pg);
    pv_mfma<<<dim3(BH, 32), 256, 0, stream>>>(Pg, v, out);
  }
}